// Round 13
// baseline (188.661 us; speedup 1.0000x reference)
//
#include <hip/hip_runtime.h>
#include <hip/hip_bf16.h>

// AttentionMechanismVaswani: B=2, G=2048, D=128, H=8, K=V=16
// *** ROUND 13 = MEASUREMENT ROUND 2: proj x4 AND flash x4 (both idempotent).
// *** T_proj+gap = (dur_r13 - dur_r12)/3; cross-check vs r11.
// *** Kernels byte-identical to r11/r12.
constexpr int Gc = 2048, Dc = 128, Hc = 8, Kc = 16;
constexpr int NCT = 24;       // proj col-tiles (8 Q, 8 K, 8 V)
constexpr int NCH = 128;      // G/16 kv-chunks
constexpr int SPLIT = 8;      // kv-split factor == waves per flash block
constexpr int QPW = 2;        // q-tiles per wave
constexpr int CPS = NCH / SPLIT;  // 16 chunks per wave

typedef __attribute__((ext_vector_type(8))) short bf16x8;
typedef __attribute__((ext_vector_type(8))) unsigned short u16x8;
typedef __attribute__((ext_vector_type(4))) unsigned int u32x4;
typedef __attribute__((ext_vector_type(4))) float f32x4;

// f32 -> bf16 (RNE) raw bits; hi/lo split gives ~2^-17 relative precision.
static __device__ __forceinline__ unsigned short f2bf(float f) {
  unsigned int u = __float_as_uint(f);
  u += 0x7FFFu + ((u >> 16) & 1u);
  return (unsigned short)(u >> 16);
}
static __device__ __forceinline__ float bf2f(unsigned short s) {
  return __uint_as_float(((unsigned int)s) << 16);
}
// single-instruction 2^x: v_exp_f32 (hardware transcendental)
static __device__ __forceinline__ float fexp2(float x) {
  float r;
  asm("v_exp_f32 %0, %1" : "=v"(r) : "v"(x));
  return r;
}
// single-instruction pack: D.lo = bf16(a), D.hi = bf16(b)
static __device__ __forceinline__ unsigned int pk_bf16(float a, float b) {
  unsigned int r;
  asm("v_cvt_pk_bf16_f32 %0, %1, %2" : "=v"(r) : "v"(a), "v"(b));
  return r;
}

// ---------------------------------------------------------------------------
// Fused projection GEMM (unchanged from r11): C[4096,384] = h*[c*Wq|Wk|Wv].
// ---------------------------------------------------------------------------
__global__ __launch_bounds__(256) void proj_gemm_kernel(
    const float* __restrict__ h, const float* __restrict__ Wq,
    const float* __restrict__ Wk, const float* __restrict__ Wv,
    unsigned short* __restrict__ Qhi, unsigned short* __restrict__ Qlo,
    unsigned short* __restrict__ Khi, unsigned short* __restrict__ Klo,
    unsigned short* __restrict__ Vf) {
  const int widx = blockIdx.x * 4 + (threadIdx.x >> 6);  // 0..6143
  const int ct = widx % NCT;
  const int rt = widx / NCT;
  const int l = threadIdx.x & 63;
  const int lane15 = l & 15, g4 = l >> 4;
  const int row0 = rt * 16;
  const int mat = ct >> 3, hh = ct & 7;

  const float* W = (mat == 0 ? Wq : (mat == 1 ? Wk : Wv)) + hh * (Dc * Kc);
  const float scale = (mat == 0) ? 0.25f * 1.44269504088896f : 1.0f;
  const float* hp = h + (size_t)(row0 + lane15) * Dc + g4 * 8;

  f32x4 acc = {0.f, 0.f, 0.f, 0.f};
#pragma unroll
  for (int kc = 0; kc < 4; ++kc) {
    const float4 v0 = *(const float4*)(hp + kc * 32);
    const float4 v1 = *(const float4*)(hp + kc * 32 + 4);
    const float av[8] = {v0.x, v0.y, v0.z, v0.w, v1.x, v1.y, v1.z, v1.w};
    bf16x8 ah, al;
#pragma unroll
    for (int i = 0; i < 8; ++i) {
      const unsigned short hb = f2bf(av[i]);
      ah[i] = (short)hb;
      al[i] = (short)f2bf(av[i] - bf2f(hb));
    }
    bf16x8 bh, bl;
#pragma unroll
    for (int j = 0; j < 8; ++j) {
      const float w = W[(kc * 32 + g4 * 8 + j) * Kc + lane15] * scale;
      const unsigned short hb = f2bf(w);
      bh[j] = (short)hb;
      bl[j] = (short)f2bf(w - bf2f(hb));
    }
    acc = __builtin_amdgcn_mfma_f32_16x16x32_bf16(ah, bh, acc, 0, 0, 0);
    acc = __builtin_amdgcn_mfma_f32_16x16x32_bf16(ah, bl, acc, 0, 0, 0);
    acc = __builtin_amdgcn_mfma_f32_16x16x32_bf16(al, bh, acc, 0, 0, 0);
  }

  const int b = row0 >> 11;
  const int g0 = row0 & 2047;
  const int bhh = b * Hc + hh;
  if (mat <= 1) {
    unsigned short* dhi = (mat == 0) ? Qhi : Khi;
    unsigned short* dlo = (mat == 0) ? Qlo : Klo;
#pragma unroll
    for (int i = 0; i < 4; ++i) {
      const size_t off = ((size_t)bhh * Gc + g0 + g4 * 4 + i) * Kc + lane15;
      const unsigned short hb = f2bf(acc[i]);
      dhi[off] = hb;
      dlo[off] = f2bf(acc[i] - bf2f(hb));
    }
  } else {
    const int c = g0 >> 4;
    u16x8 fv;
#pragma unroll
    for (int i = 0; i < 4; ++i) {
      const unsigned short hb = f2bf(acc[i]);
      fv[i] = hb;
      fv[i + 4] = f2bf(acc[i] - bf2f(hb));
    }
    *(u16x8*)(Vf + ((size_t)(bhh * NCH + c) * 64 + l) * 8) = fv;
  }
}

// ---------------------------------------------------------------------------
// Flash attention (unchanged from r11).
// ---------------------------------------------------------------------------
__global__ __launch_bounds__(512, 6) void flash_kernel(
    const unsigned short* __restrict__ Qhi, const unsigned short* __restrict__ Qlo,
    const unsigned short* __restrict__ Khi, const unsigned short* __restrict__ Klo,
    const unsigned short* __restrict__ Vf, float* __restrict__ out) {
  __shared__ f32x4 lo_s[SPLIT][QPW][64];   // 16 KB
  __shared__ float lml[SPLIT][QPW][16][2]; // 2 KB

  const int qg = blockIdx.x;            // 0..1023 q-tile pairs
  const int split = threadIdx.x >> 6;   // 0..7
  const int bh = qg >> 6;               // 64 pairs per (b,h)
  const int qi0 = (qg & 63) * QPW;
  const int l = threadIdx.x & 63;
  const int lane15 = l & 15, g4 = l >> 4, dhalf = g4 & 1;

  bf16x8 bqh[QPW], bql[QPW];
#pragma unroll
  for (int t = 0; t < QPW; ++t) {
    const size_t qoff =
        ((size_t)bh * Gc + (qi0 + t) * 16 + lane15) * Kc + 8 * dhalf;
    bqh[t] = *(const bf16x8*)(Qhi + qoff);
    bql[t] = *(const bf16x8*)(Qlo + qoff);
  }

  const unsigned short* kbase = (g4 >= 2 ? Klo : Khi) +
      (size_t)bh * Gc * Kc + lane15 * Kc + 8 * dhalf + (size_t)split * CPS * 256;
  const unsigned short* vbase =
      Vf + ((size_t)bh * NCH * 64 + l) * 8 + (size_t)split * CPS * 512;

  const f32x4 z = {0.f, 0.f, 0.f, 0.f};
  f32x4 o[QPW] = {z, z};
  float run_max = -1e30f, thr = -1e30f;
  float lsum[QPW] = {0.f, 0.f};

#pragma unroll 4
  for (int c = 0; c < CPS; ++c) {
    const bf16x8 ak = *(const bf16x8*)(kbase + (size_t)c * 256);
    const bf16x8 av = *(const bf16x8*)(vbase + (size_t)c * 512);

    f32x4 s[QPW];
#pragma unroll
    for (int t = 0; t < QPW; ++t) {
      f32x4 tmp = __builtin_amdgcn_mfma_f32_16x16x32_bf16(ak, bql[t], z, 0, 0, 0);
      s[t] = __builtin_amdgcn_mfma_f32_16x16x32_bf16(ak, bqh[t], tmp, 0, 0, 0);
    }

    float cm = fmaxf(fmaxf(s[0][0], s[0][1]), fmaxf(s[0][2], s[0][3]));
    cm = fmaxf(cm, fmaxf(fmaxf(s[1][0], s[1][1]), fmaxf(s[1][2], s[1][3])));
    if (!__all((int)(cm <= thr))) {
      float fm = fmaxf(cm, __shfl_xor(cm, 16));
      fm = fmaxf(fm, __shfl_xor(fm, 32));
      const float nm = fmaxf(run_max, fm);
      const float corr = fexp2(run_max - nm);
#pragma unroll
      for (int t = 0; t < QPW; ++t) {
        o[t][0] *= corr; o[t][1] *= corr; o[t][2] *= corr; o[t][3] *= corr;
        lsum[t] *= corr;
      }
      run_max = nm;
      thr = nm + 11.5f;
    }

#pragma unroll
    for (int t = 0; t < QPW; ++t) {
      const float p0 = fexp2(s[t][0] - run_max);
      const float p1 = fexp2(s[t][1] - run_max);
      const float p2 = fexp2(s[t][2] - run_max);
      const float p3 = fexp2(s[t][3] - run_max);
      lsum[t] += (p0 + p1) + (p2 + p3);

      const unsigned int w01 = pk_bf16(p0, p1);
      const unsigned int w23 = pk_bf16(p2, p3);
      const u32x4 bpv = {w01, w23, w01, w23};
      const bf16x8 bp = __builtin_bit_cast(bf16x8, bpv);
      o[t] = __builtin_amdgcn_mfma_f32_16x16x32_bf16(av, bp, o[t], 0, 0, 0);
    }
  }

#pragma unroll
  for (int t = 0; t < QPW; ++t) {
    float ls = lsum[t];
    ls += __shfl_xor(ls, 16);
    ls += __shfl_xor(ls, 32);
    lo_s[split][t][l] = o[t];
    if (l < 16) {
      lml[split][t][l][0] = run_max;
      lml[split][t][l][1] = ls;
    }
  }
  __syncthreads();

  if (threadIdx.x < QPW * 64) {
    const int t = split;
    float m[SPLIT], lv[SPLIT];
#pragma unroll
    for (int s = 0; s < SPLIT; ++s) {
      m[s] = lml[s][t][lane15][0];
      lv[s] = lml[s][t][lane15][1];
    }
    float M = m[0];
#pragma unroll
    for (int s = 1; s < SPLIT; ++s) M = fmaxf(M, m[s]);
    f32x4 acc = {0.f, 0.f, 0.f, 0.f};
    float den = 0.f;
#pragma unroll
    for (int s = 0; s < SPLIT; ++s) {
      const float w = fexp2(m[s] - M);
      den += w * lv[s];
      const f32x4 po = lo_s[s][t][l];
      acc[0] += w * po[0]; acc[1] += w * po[1];
      acc[2] += w * po[2]; acc[3] += w * po[3];
    }
    const float inv = 1.0f / den;
    f32x4 res;
    res[0] = acc[0] * inv; res[1] = acc[1] * inv;
    res[2] = acc[2] * inv; res[3] = acc[3] * inv;
    *(f32x4*)(out + ((size_t)bh * Gc + (qi0 + t) * 16 + lane15) * Kc + 4 * g4) =
        res;
  }
}

extern "C" void kernel_launch(void* const* d_in, const int* in_sizes, int n_in,
                              void* d_out, int out_size, void* d_ws, size_t ws_size,
                              hipStream_t stream) {
  const float* h  = (const float*)d_in[0];
  const float* Wq = (const float*)d_in[1];
  const float* Wk = (const float*)d_in[2];
  const float* Wv = (const float*)d_in[3];
  float* out = (float*)d_out;

  char* ws = (char*)d_ws;
  unsigned short* Qhi = (unsigned short*)(ws);                // 1 MB
  unsigned short* Qlo = (unsigned short*)(ws + (1u << 20));   // 1 MB
  unsigned short* Khi = (unsigned short*)(ws + (2u << 20));   // 1 MB
  unsigned short* Klo = (unsigned short*)(ws + (3u << 20));   // 1 MB
  unsigned short* Vf  = (unsigned short*)(ws + (4u << 20));   // 2 MB

  // MEASUREMENT: 4x proj + 4x flash (both idempotent).
  // T_proj+gap = (dur_r13 - dur_r12)/3; flash number cross-checks vs r11.
  proj_gemm_kernel<<<1536, 256, 0, stream>>>(h, Wq, Wk, Wv, Qhi, Qlo, Khi, Klo,
                                             Vf);
  proj_gemm_kernel<<<1536, 256, 0, stream>>>(h, Wq, Wk, Wv, Qhi, Qlo, Khi, Klo,
                                             Vf);
  proj_gemm_kernel<<<1536, 256, 0, stream>>>(h, Wq, Wk, Wv, Qhi, Qlo, Khi, Klo,
                                             Vf);
  proj_gemm_kernel<<<1536, 256, 0, stream>>>(h, Wq, Wk, Wv, Qhi, Qlo, Khi, Klo,
                                             Vf);
  flash_kernel<<<1024, 512, 0, stream>>>(Qhi, Qlo, Khi, Klo, Vf, out);
  flash_kernel<<<1024, 512, 0, stream>>>(Qhi, Qlo, Khi, Klo, Vf, out);
  flash_kernel<<<1024, 512, 0, stream>>>(Qhi, Qlo, Khi, Klo, Vf, out);
  flash_kernel<<<1024, 512, 0, stream>>>(Qhi, Qlo, Khi, Klo, Vf, out);
}

// Round 14
// 92.821 us; speedup vs baseline: 2.0325x; 2.0325x over previous
//
#include <hip/hip_runtime.h>
#include <hip/hip_bf16.h>

// AttentionMechanismVaswani: B=2, G=2048, D=128, H=8, K=V=16
constexpr int Gc = 2048, Dc = 128, Hc = 8, Kc = 16;
constexpr int NCT = 24;       // proj col-tiles (8 Q, 8 K, 8 V)
constexpr int NCH = 128;      // G/16 kv-chunks
constexpr int SPLIT = 8;      // kv-split factor == waves per flash block
constexpr int QPW = 2;        // q-tiles per wave
constexpr int CPS = NCH / SPLIT;  // 16 chunks per wave

typedef __attribute__((ext_vector_type(8))) short bf16x8;
typedef __attribute__((ext_vector_type(4))) unsigned short u16x4;
typedef __attribute__((ext_vector_type(8))) unsigned short u16x8;
typedef __attribute__((ext_vector_type(4))) unsigned int u32x4;
typedef __attribute__((ext_vector_type(4))) float f32x4;

// f32 -> bf16 (RNE) raw bits; hi/lo split gives ~2^-17 relative precision.
static __device__ __forceinline__ unsigned short f2bf(float f) {
  unsigned int u = __float_as_uint(f);
  u += 0x7FFFu + ((u >> 16) & 1u);
  return (unsigned short)(u >> 16);
}
static __device__ __forceinline__ float bf2f(unsigned short s) {
  return __uint_as_float(((unsigned int)s) << 16);
}
// single-instruction 2^x: v_exp_f32 (hardware transcendental)
static __device__ __forceinline__ float fexp2(float x) {
  float r;
  asm("v_exp_f32 %0, %1" : "=v"(r) : "v"(x));
  return r;
}
// single-instruction pack: D.lo = bf16(a), D.hi = bf16(b)
static __device__ __forceinline__ unsigned int pk_bf16(float a, float b) {
  unsigned int r;
  asm("v_cvt_pk_bf16_f32 %0, %1, %2" : "=v"(r) : "v"(a), "v"(b));
  return r;
}

// ---------------------------------------------------------------------------
// Prep: split ONCE what r9-r13's proj redundantly re-split 24-256x per tile
// (that redundancy was measured at ~12 us; this kernel is ~1.5 us of traffic).
// blocks 0..511: h [4096][128] f32 -> bf16 hi/lo.
// blocks 512..535: W -> B-fragment layout hi/lo; W_Q scaled by 0.25*log2(e).
// ---------------------------------------------------------------------------
__global__ __launch_bounds__(256) void prep_kernel(
    const float* __restrict__ h, const float* __restrict__ Wq,
    const float* __restrict__ Wk, const float* __restrict__ Wv,
    unsigned short* __restrict__ hhi, unsigned short* __restrict__ hlo,
    unsigned short* __restrict__ WfH, unsigned short* __restrict__ WfL) {
  if (blockIdx.x < 512) {
    const int t = blockIdx.x * 256 + threadIdx.x;  // 131072 threads, 4 elems
    const float4 v = *(const float4*)(h + (size_t)t * 4);
    const float a[4] = {v.x, v.y, v.z, v.w};
    u16x4 hi, lo;
#pragma unroll
    for (int i = 0; i < 4; ++i) {
      const unsigned short hb = f2bf(a[i]);
      hi[i] = hb;
      lo[i] = f2bf(a[i] - bf2f(hb));
    }
    *(u16x4*)(hhi + (size_t)t * 4) = hi;
    *(u16x4*)(hlo + (size_t)t * 4) = lo;
  } else {
    const int t = (blockIdx.x - 512) * 256 + threadIdx.x;  // 6144: (ct,kc,l)
    const int l = t & 63;
    const int kc = (t >> 6) & 3;
    const int ct = t >> 8;
    const int mat = ct >> 3, hh = ct & 7;
    const float* W = (mat == 0 ? Wq : (mat == 1 ? Wk : Wv)) + hh * (Dc * Kc);
    const float scale = (mat == 0) ? 0.25f * 1.44269504088896f : 1.0f;
    const int col = l & 15, g4 = l >> 4;
    u16x8 hi, lo;
#pragma unroll
    for (int j = 0; j < 8; ++j) {
      const int d = kc * 32 + g4 * 8 + j;
      const float w = W[d * Kc + col] * scale;
      const unsigned short hb = f2bf(w);
      hi[j] = hb;
      lo[j] = f2bf(w - bf2f(hb));
    }
    *(u16x8*)(WfH + (size_t)t * 8) = hi;
    *(u16x8*)(WfL + (size_t)t * 8) = lo;
  }
}

// ---------------------------------------------------------------------------
// Fused projection GEMM: C[4096,384] = h*[c*Wq|Wk|Wv] from PRE-SPLIT
// fragments (hh*wh + hh*wl + hl*wh; lo*lo dropped, ~2^-18). One wave per
// 16x16 tile; only loads + 12 MFMA + epilogue split remain.
// Epilogues: Q,K -> hi/lo bf16 row-major [bh][g][16];
//            V   -> merged [vh|vl] PV A-fragment [bh][chunk][64][8].
// ---------------------------------------------------------------------------
__global__ __launch_bounds__(256) void proj_gemm_kernel(
    const unsigned short* __restrict__ hhi, const unsigned short* __restrict__ hlo,
    const unsigned short* __restrict__ WfH, const unsigned short* __restrict__ WfL,
    unsigned short* __restrict__ Qhi, unsigned short* __restrict__ Qlo,
    unsigned short* __restrict__ Khi, unsigned short* __restrict__ Klo,
    unsigned short* __restrict__ Vf) {
  const int widx = blockIdx.x * 4 + (threadIdx.x >> 6);  // 0..6143
  const int ct = widx % NCT;
  const int rt = widx / NCT;
  const int l = threadIdx.x & 63;
  const int lane15 = l & 15, g4 = l >> 4;
  const int row0 = rt * 16;

  const unsigned short* ah_p = hhi + (size_t)(row0 + lane15) * Dc + g4 * 8;
  const unsigned short* al_p = hlo + (size_t)(row0 + lane15) * Dc + g4 * 8;
  const unsigned short* bh_p = WfH + (size_t)ct * 2048 + l * 8;
  const unsigned short* bl_p = WfL + (size_t)ct * 2048 + l * 8;

  f32x4 acc = {0.f, 0.f, 0.f, 0.f};
#pragma unroll
  for (int kc = 0; kc < 4; ++kc) {
    const bf16x8 ah = *(const bf16x8*)(ah_p + kc * 32);
    const bf16x8 al = *(const bf16x8*)(al_p + kc * 32);
    const bf16x8 bh = *(const bf16x8*)(bh_p + kc * 512);
    const bf16x8 bl = *(const bf16x8*)(bl_p + kc * 512);
    acc = __builtin_amdgcn_mfma_f32_16x16x32_bf16(ah, bh, acc, 0, 0, 0);
    acc = __builtin_amdgcn_mfma_f32_16x16x32_bf16(ah, bl, acc, 0, 0, 0);
    acc = __builtin_amdgcn_mfma_f32_16x16x32_bf16(al, bh, acc, 0, 0, 0);
  }

  // C-layout: lane holds rows row0 + 4*g4 + i, col = lane15 (within tile ct)
  const int mat = ct >> 3, hh = ct & 7;
  const int b = row0 >> 11;
  const int g0 = row0 & 2047;
  const int bhh = b * Hc + hh;
  if (mat <= 1) {
    unsigned short* dhi = (mat == 0) ? Qhi : Khi;
    unsigned short* dlo = (mat == 0) ? Qlo : Klo;
#pragma unroll
    for (int i = 0; i < 4; ++i) {
      const size_t off = ((size_t)bhh * Gc + g0 + g4 * 4 + i) * Kc + lane15;
      const unsigned short hb = f2bf(acc[i]);
      dhi[off] = hb;
      dlo[off] = f2bf(acc[i] - bf2f(hb));
    }
  } else {
    const int c = g0 >> 4;  // row-tile == one kv-chunk
    u16x8 fv;
#pragma unroll
    for (int i = 0; i < 4; ++i) {
      const unsigned short hb = f2bf(acc[i]);
      fv[i] = hb;                           // k-slots 0-3: V-hi
      fv[i + 4] = f2bf(acc[i] - bf2f(hb));  // k-slots 4-7: V-lo
    }
    *(u16x8*)(Vf + ((size_t)(bhh * NCH + c) * 64 + l) * 8) = fv;
  }
}

// ---------------------------------------------------------------------------
// Flash attention (byte-identical to r11): 2 q-tiles/wave, 8-way KV split,
// fused combine through LDS, shared defer-max, asm v_exp/cvt_pk.
// Measured at ~20.1 us (r12 multi-launch probe).
// ---------------------------------------------------------------------------
__global__ __launch_bounds__(512, 6) void flash_kernel(
    const unsigned short* __restrict__ Qhi, const unsigned short* __restrict__ Qlo,
    const unsigned short* __restrict__ Khi, const unsigned short* __restrict__ Klo,
    const unsigned short* __restrict__ Vf, float* __restrict__ out) {
  __shared__ f32x4 lo_s[SPLIT][QPW][64];   // 16 KB
  __shared__ float lml[SPLIT][QPW][16][2]; // 2 KB

  const int qg = blockIdx.x;            // 0..1023 q-tile pairs
  const int split = threadIdx.x >> 6;   // 0..7
  const int bh = qg >> 6;               // 64 pairs per (b,h)
  const int qi0 = (qg & 63) * QPW;
  const int l = threadIdx.x & 63;
  const int lane15 = l & 15, g4 = l >> 4, dhalf = g4 & 1;

  bf16x8 bqh[QPW], bql[QPW];
#pragma unroll
  for (int t = 0; t < QPW; ++t) {
    const size_t qoff =
        ((size_t)bh * Gc + (qi0 + t) * 16 + lane15) * Kc + 8 * dhalf;
    bqh[t] = *(const bf16x8*)(Qhi + qoff);
    bql[t] = *(const bf16x8*)(Qlo + qoff);
  }

  const unsigned short* kbase = (g4 >= 2 ? Klo : Khi) +
      (size_t)bh * Gc * Kc + lane15 * Kc + 8 * dhalf + (size_t)split * CPS * 256;
  const unsigned short* vbase =
      Vf + ((size_t)bh * NCH * 64 + l) * 8 + (size_t)split * CPS * 512;

  const f32x4 z = {0.f, 0.f, 0.f, 0.f};
  f32x4 o[QPW] = {z, z};
  float run_max = -1e30f, thr = -1e30f;
  float lsum[QPW] = {0.f, 0.f};

#pragma unroll 4
  for (int c = 0; c < CPS; ++c) {
    const bf16x8 ak = *(const bf16x8*)(kbase + (size_t)c * 256);
    const bf16x8 av = *(const bf16x8*)(vbase + (size_t)c * 512);

    f32x4 s[QPW];
#pragma unroll
    for (int t = 0; t < QPW; ++t) {
      f32x4 tmp = __builtin_amdgcn_mfma_f32_16x16x32_bf16(ak, bql[t], z, 0, 0, 0);
      s[t] = __builtin_amdgcn_mfma_f32_16x16x32_bf16(ak, bqh[t], tmp, 0, 0, 0);
      // s[t][i] = S^T[m = c*16 + 4*g4 + i][q = lane15], log2 units
    }

    float cm = fmaxf(fmaxf(s[0][0], s[0][1]), fmaxf(s[0][2], s[0][3]));
    cm = fmaxf(cm, fmaxf(fmaxf(s[1][0], s[1][1]), fmaxf(s[1][2], s[1][3])));
    if (!__all((int)(cm <= thr))) {
      float fm = fmaxf(cm, __shfl_xor(cm, 16));
      fm = fmaxf(fm, __shfl_xor(fm, 32));
      const float nm = fmaxf(run_max, fm);
      const float corr = fexp2(run_max - nm);  // 1st iter: exp2(-huge)=0
#pragma unroll
      for (int t = 0; t < QPW; ++t) {
        o[t][0] *= corr; o[t][1] *= corr; o[t][2] *= corr; o[t][3] *= corr;
        lsum[t] *= corr;
      }
      run_max = nm;
      thr = nm + 11.5f;  // ~8 nats of defer-max headroom
    }

#pragma unroll
    for (int t = 0; t < QPW; ++t) {
      const float p0 = fexp2(s[t][0] - run_max);
      const float p1 = fexp2(s[t][1] - run_max);
      const float p2 = fexp2(s[t][2] - run_max);
      const float p3 = fexp2(s[t][3] - run_max);
      lsum[t] += (p0 + p1) + (p2 + p3);

      const unsigned int w01 = pk_bf16(p0, p1);
      const unsigned int w23 = pk_bf16(p2, p3);
      const u32x4 bpv = {w01, w23, w01, w23};
      const bf16x8 bp = __builtin_bit_cast(bf16x8, bpv);
      o[t] = __builtin_amdgcn_mfma_f32_16x16x32_bf16(av, bp, o[t], 0, 0, 0);
    }
  }

#pragma unroll
  for (int t = 0; t < QPW; ++t) {
    float ls = lsum[t];
    ls += __shfl_xor(ls, 16);
    ls += __shfl_xor(ls, 32);
    lo_s[split][t][l] = o[t];
    if (l < 16) {
      lml[split][t][l][0] = run_max;
      lml[split][t][l][1] = ls;
    }
  }
  __syncthreads();

  if (threadIdx.x < QPW * 64) {  // wave t merges q-tile qi0+t
    const int t = split;  // 0..QPW-1 here
    float m[SPLIT], lv[SPLIT];
#pragma unroll
    for (int s = 0; s < SPLIT; ++s) {
      m[s] = lml[s][t][lane15][0];
      lv[s] = lml[s][t][lane15][1];
    }
    float M = m[0];
#pragma unroll
    for (int s = 1; s < SPLIT; ++s) M = fmaxf(M, m[s]);
    f32x4 acc = {0.f, 0.f, 0.f, 0.f};
    float den = 0.f;
#pragma unroll
    for (int s = 0; s < SPLIT; ++s) {
      const float w = fexp2(m[s] - M);
      den += w * lv[s];
      const f32x4 po = lo_s[s][t][l];
      acc[0] += w * po[0]; acc[1] += w * po[1];
      acc[2] += w * po[2]; acc[3] += w * po[3];
    }
    const float inv = 1.0f / den;
    f32x4 res;
    res[0] = acc[0] * inv; res[1] = acc[1] * inv;
    res[2] = acc[2] * inv; res[3] = acc[3] * inv;
    *(f32x4*)(out + ((size_t)bh * Gc + (qi0 + t) * 16 + lane15) * Kc + 4 * g4) =
        res;
  }
}

extern "C" void kernel_launch(void* const* d_in, const int* in_sizes, int n_in,
                              void* d_out, int out_size, void* d_ws, size_t ws_size,
                              hipStream_t stream) {
  const float* h  = (const float*)d_in[0];
  const float* Wq = (const float*)d_in[1];
  const float* Wk = (const float*)d_in[2];
  const float* Wv = (const float*)d_in[3];
  float* out = (float*)d_out;

  char* ws = (char*)d_ws;
  unsigned short* Qhi = (unsigned short*)(ws);                // 1 MB
  unsigned short* Qlo = (unsigned short*)(ws + (1u << 20));   // 1 MB
  unsigned short* Khi = (unsigned short*)(ws + (2u << 20));   // 1 MB
  unsigned short* Klo = (unsigned short*)(ws + (3u << 20));   // 1 MB
  unsigned short* Vf  = (unsigned short*)(ws + (4u << 20));   // 2 MB
  unsigned short* hhi = (unsigned short*)(ws + (6u << 20));   // 1 MB
  unsigned short* hlo = (unsigned short*)(ws + (7u << 20));   // 1 MB
  unsigned short* WfH = (unsigned short*)(ws + (8u << 20));   // 96 KB
  unsigned short* WfL = (unsigned short*)(ws + (8u << 20) + (1u << 18));

  prep_kernel<<<536, 256, 0, stream>>>(h, Wq, Wk, Wv, hhi, hlo, WfH, WfL);
  proj_gemm_kernel<<<1536, 256, 0, stream>>>(hhi, hlo, WfH, WfL, Qhi, Qlo, Khi,
                                             Klo, Vf);
  flash_kernel<<<1024, 512, 0, stream>>>(Qhi, Qlo, Khi, Klo, Vf, out);
}